// Round 12
// baseline (2287.623 us; speedup 1.0000x reference)
//
#include <hip/hip_runtime.h>

typedef float  f32x4  __attribute__((ext_vector_type(4)));
typedef short  bf16x8 __attribute__((ext_vector_type(8)));

#define DEVI static __device__ __forceinline__

namespace {
constexpr int kL   = 512;
constexpr int kN   = 64;
constexpr int kDH  = 512;
constexpr int kDIN = 512;
constexpr int kG   = 2048;            // 4*kDH
constexpr int kT   = 32;              // timesteps per chunk
constexpr int kChunks = kL / kT;      // 16
constexpr int kHS  = kN * kDH;        // 32768 elements per step slice
constexpr int kFP  = 16;              // flag padding: 1 flag per 64B line
constexpr int kRB  = 32;              // rec blocks (512 threads, 2 cg-chunks each)
constexpr size_t kOutSz = (size_t)kL * kN * kDIN;  // 16,777,216 floats
}

// hsx layout (bf16): [t][chunk=c/8][w=n/16][n%16][c%8]  (R7 win)
// flags: one per 64B line, wave0-poll + barrier + block publish (R8 win)
// Zx layout: [cg][t][lane256][8], 32B contiguous per lane (R10 win)
// B-fragments: preloaded to 128 VGPRs once, direct from global WhB (R10 win)
// R12: 32 rec blocks x 512 threads (8 waves = 4 batch-planes x 2 cg-chunks):
//   convoy max over 32 (was 64), 32 flag publishes + 32 poll targets per step.
//   gemm role = two independent 256-thread halves per block with a PADDED
//   predicated tile loop (uniform __syncthreads counts across halves).

DEVI unsigned short f2bf(float f) {
  union { float f; unsigned u; } v; v.f = f;
  unsigned r = v.u + 0x7FFFu + ((v.u >> 16) & 1u);   // RNE
  return (unsigned short)(r >> 16);
}
DEVI float sigm(float z) { return 1.f / (1.f + __expf(-z)); }
DEVI float tanh_f(float z) { return 2.f / (1.f + __expf(-2.f * z)) - 1.f; }

// ---------------------------------------------------------------- prep
__global__ void prep_kernel(
    const float* __restrict__ Wf, const float* __restrict__ Wc,
    const float* __restrict__ Wi, const float* __restrict__ Wo,
    const float* __restrict__ bf, const float* __restrict__ bc,
    const float* __restrict__ bi, const float* __restrict__ bo,
    const float* __restrict__ Wout,
    const float* __restrict__ h0, const float* __restrict__ c0,
    unsigned short* __restrict__ WxT, unsigned short* __restrict__ WoT,
    unsigned short* __restrict__ WhB, float* __restrict__ bg,
    unsigned short* __restrict__ hsx, float* __restrict__ cbuf,
    unsigned int* __restrict__ flags)
{
  const int gid = blockIdx.x * blockDim.x + threadIdx.x;
  const int stride = gridDim.x * blockDim.x;
  const float* Wg[4]  = {Wf, Wc, Wi, Wo};
  const float* bgs[4] = {bf, bc, bi, bo};

  for (int i = gid; i < kRB * kFP; i += stride) flags[i] = 0u;

  for (int i = gid; i < kG * 512; i += stride) {
    int k = i >> 11, g = i & 2047;
    WxT[(size_t)g * 512 + k] = f2bf(Wg[g >> 9][(size_t)k * 512 + (g & 511)]);
  }
  for (int i = gid; i < 512 * 512; i += stride) {
    int k = i >> 9, c = i & 511;
    WoT[(size_t)c * 512 + k] = f2bf(Wout[(size_t)k * 512 + c]);
  }
  // WhB: i = k*1024 + gate*512 + hcol  -> coalesced source reads
  for (int i = gid; i < 4 * 512 * 512; i += stride) {
    int hcol = i & 511;
    int gate = (i >> 9) & 3;
    int k    = i >> 11;
    int cg = hcol >> 3, jj = hcol & 7;
    int n  = gate * 8 + jj;
    int kblk = k >> 3, kin = k & 7;
    size_t dst = ((size_t)cg * 32 + n) * 512 + (((kblk ^ (n & 7)) << 3) | kin);
    WhB[dst] = f2bf(Wg[gate][(size_t)(512 + k) * 512 + hcol]);
  }
  for (int i = gid; i < kG; i += stride) bg[i] = bgs[i >> 9][i & 511];
  for (int i = gid; i < kN * kDH; i += stride) {
    int n = i >> 9, c = i & 511;   // h0[n][c]
    hsx[((size_t)(c >> 3)) * 512 + ((n >> 4) * 128) + ((n & 15) * 8) + (c & 7)]
        = f2bf(h0[i]);             // hsx[0] in chunked layout
    cbuf[i] = c0[i];
  }
}

// Shared memory for one 256-thread gemm worker.
struct GS {
  unsigned short Ash[128][40];
  unsigned short Bsh[128][40];
};

// ---------------------------------------------------------------- gemm_x body
// z[row][col] with col = gate*512 + cg*8 + jj; n = gate*8+jj; q=n&15, half=n>>4.
// Write lane-swizzled Zx: [(cg*32 + t)*256 + (w*64+lg*16+q)]*8 + i*2 + half.
// `active=false` executes all barriers (uniform counts) but no global traffic.
DEVI void gemm_x_tile(GS& sm, const float* __restrict__ X,
                      const unsigned short* __restrict__ WxT,
                      const float* __restrict__ bg,
                      float* __restrict__ Zx2, int row0, int col0, int tid,
                      bool active)
{
  const int lane = tid & 63, wave = tid >> 6;
  const int wr = wave >> 1, wc = wave & 1;
  const int m16 = lane & 15, kg = (lane >> 4) * 8;

  f32x4 acc[4][4] = {};

  for (int k0 = 0; k0 < 512; k0 += 32) {
    __syncthreads();
    if (active) {
      #pragma unroll
      for (int i = 0; i < 4; ++i) {
        int idx = i * 256 + tid;
        int r = idx >> 3, kq = idx & 7;
        float4 v = *(const float4*)&X[(size_t)(row0 + r) * 512 + k0 + kq * 4];
        unsigned short* dst = &sm.Ash[r][kq * 4];
        dst[0] = f2bf(v.x); dst[1] = f2bf(v.y); dst[2] = f2bf(v.z); dst[3] = f2bf(v.w);
      }
      #pragma unroll
      for (int i = 0; i < 2; ++i) {
        int idx = i * 256 + tid;
        int c = idx >> 2, kq = idx & 3;
        *(uint4*)&sm.Bsh[c][kq * 8] =
            *(const uint4*)&WxT[(size_t)(col0 + c) * 512 + k0 + kq * 8];
      }
    }
    __syncthreads();
    bf16x8 fa[4], fb[4];
    #pragma unroll
    for (int mi = 0; mi < 4; ++mi) fa[mi] = *(const bf16x8*)&sm.Ash[wr*64 + mi*16 + m16][kg];
    #pragma unroll
    for (int ni = 0; ni < 4; ++ni) fb[ni] = *(const bf16x8*)&sm.Bsh[wc*64 + ni*16 + m16][kg];
    #pragma unroll
    for (int mi = 0; mi < 4; ++mi)
      #pragma unroll
      for (int ni = 0; ni < 4; ++ni)
        acc[mi][ni] = __builtin_amdgcn_mfma_f32_16x16x32_bf16(fa[mi], fb[ni], acc[mi][ni], 0, 0, 0);
  }
  if (!active) return;   // after final barrier above; no more barriers below
  const int rg = (lane >> 4) * 4;
  #pragma unroll
  for (int ni = 0; ni < 4; ++ni) {
    int col = col0 + wc*64 + ni*16 + m16;
    float bb = bg[col];
    int gate = col >> 9, hcol = col & 511;
    int cg = hcol >> 3, n = gate * 8 + (hcol & 7);
    int qn = n & 15, half = n >> 4;
    #pragma unroll
    for (int mi = 0; mi < 4; ++mi)
      #pragma unroll
      for (int r = 0; r < 4; ++r) {
        int row = row0 + wr*64 + mi*16 + rg + r;
        int t = row >> 6, b = row & 63;
        int wv = b >> 4, lgv = (b >> 2) & 3, iv = b & 3;
        Zx2[((size_t)(cg * 32 + t) * 256 + (wv * 64 + lgv * 16 + qn)) * 8 +
            iv * 2 + half] = acc[mi][ni][r] + bb;
      }
  }
}

// ---------------------------------------------------------------- gemm_x (standalone, chunk 0; 256 threads)
__global__ __launch_bounds__(256) void gemm_x_kernel(
    const float* __restrict__ X, const unsigned short* __restrict__ WxT,
    const float* __restrict__ bg, float* __restrict__ Zx2)
{
  __shared__ GS sm;
  gemm_x_tile(sm, X, WxT, bg, Zx2, blockIdx.x * 128, blockIdx.y * 128,
              threadIdx.x, true);
}

// ---------------------------------------------------------------- fused: rec (blk 0..31) + next-chunk gemm_x (blk 32..127), 512 threads
__global__ __launch_bounds__(512, 1) void lstm_fused_kernel(
    const unsigned short* __restrict__ WhB,  // [64][32][512] bf16 swizzled
    const float* __restrict__ Zxcur,         // [64][32][256][8] lane-swizzled
    unsigned short* __restrict__ hsx,        // [513][...] bf16, chunked layout
    float* __restrict__ cbuf,                // [64][512] fp32
    int step0,
    unsigned int* __restrict__ flags,        // [kRB*kFP], flag at bi*kFP
    float* __restrict__ dout,
    const float* __restrict__ Xnext,         // next chunk x (null on last)
    const unsigned short* __restrict__ WxT,
    const float* __restrict__ bg,
    float* __restrict__ Zxnext)              // next chunk Zx buffer
{
  __shared__ GS sm2[2];                      // 40 KB (gemm role only)
  const int tid = threadIdx.x;

  if (blockIdx.x >= kRB) {
    // ------- gemm role: 96 blocks x 2 halves = 192 workers, 256 tiles -------
    if (Xnext == nullptr) return;
    const int half = tid >> 8, t256 = tid & 255;
    const int worker = ((int)blockIdx.x - kRB) * 2 + half;   // 0..191
    #pragma unroll 1
    for (int i = 0; i < 2; ++i) {
      int tile = worker + i * 192;
      bool active = (tile < 256);
      gemm_x_tile(sm2[half], Xnext, WxT, bg, Zxnext,
                  (tile >> 4) * 128, (tile & 15) * 128, t256, active);
      __syncthreads();
    }
    return;
  }

  // ---------------- rec role: 8 waves = 4 batch-planes x 2 cg-chunks --------
  const int bi = blockIdx.x;          // 0..31
  const int v  = tid >> 6;            // wave 0..7
  const int l  = tid & 63;
  const int w  = v & 3;               // batch plane (rows w*16..+15)
  const int cg = bi * 2 + (v >> 2);   // column chunk (cols cg*8..+7)
  const int j0 = cg * 8;
  const int q  = l & 15;              // n-col within frag
  const int lg = l >> 4;              // k-group
  const int jj = q & 7;
  const int i0 = (q < 8) ? 0 : 2;     // acc rows this lane finishes

  // one-time: preload ALL B fragments straight from global WhB (no LDS).
  const unsigned short* Wgp = WhB + (size_t)cg * 32 * 512;
  bf16x8 B0[16], B1[16];
  #pragma unroll
  for (int s = 0; s < 16; ++s) {
    const int kb = 4 * s + lg;
    B0[s] = *(const bf16x8*)&Wgp[(size_t)q * 512 + ((kb ^ jj) << 3)];
    B1[s] = *(const bf16x8*)&Wgp[(size_t)(16 + q) * 512 + ((kb ^ jj) << 3)];
  }

  const size_t cidx = (size_t)(w * 16 + lg * 4 + i0) * 512 + j0 + jj;
  float c0r = cbuf[cidx];
  float c1r = cbuf[cidx + 512];

  // Zx base for this lane (R10 layout: lane256 = w*64 + l)
  const float* zbase = Zxcur + (size_t)cg * 32 * 2048 + (size_t)(w * 64 + l) * 8;
  float zc0[4], zc1[4];
  {
    f32x4 a = *(const f32x4*)zbase;
    f32x4 b = *(const f32x4*)(zbase + 4);
    zc0[0] = a[0]; zc1[0] = a[1]; zc0[1] = a[2]; zc1[1] = a[3];
    zc0[2] = b[0]; zc1[2] = b[1]; zc0[3] = b[2]; zc1[3] = b[3];
  }

  for (int t = 0; t < kT; ++t) {
    const int st = step0 + t;

    // gate: wave 0 polls the 32 padded flags (lanes 32..63 mirror 0..31);
    // other waves wait at the barrier. (t=0: previous dispatch completed.)
    if (t > 0) {
      if (tid < 64) {
        for (;;) {
          int fv = (int)__hip_atomic_load(&flags[(l & 31) * kFP],
                                          __ATOMIC_RELAXED,
                                          __HIP_MEMORY_SCOPE_AGENT);
          if (__all(fv >= st)) break;
        }
      }
      __syncthreads();
    }

    // A-frags from chunked layout: A[s] = row w*16+q, cols 8*(4s+lg)..+7
    const unsigned short* hrow =
        hsx + (size_t)st * kHS + (size_t)lg * 512 + w * 128 + q * 8;
    bf16x8 A[16];
    #pragma unroll
    for (int s = 0; s < 16; ++s) A[s] = *(const bf16x8*)(hrow + 2048 * s);

    // Zx prefetch for t+1 issued BEFORE MFMA: completes under compute.
    float zn0[4], zn1[4];
    if (t + 1 < kT) {
      const float* zb = zbase + (size_t)(t + 1) * 2048;
      f32x4 a = *(const f32x4*)zb;
      f32x4 b = *(const f32x4*)(zb + 4);
      zn0[0] = a[0]; zn1[0] = a[1]; zn0[1] = a[2]; zn1[1] = a[3];
      zn0[2] = b[0]; zn1[2] = b[1]; zn0[3] = b[2]; zn1[3] = b[3];
    }

    // MFMA: 16 ksteps x 2 n-frags, B from registers (no LDS in loop)
    f32x4 acc0 = {}, acc1 = {};
    #pragma unroll
    for (int s = 0; s < 16; ++s) {
      acc0 = __builtin_amdgcn_mfma_f32_16x16x32_bf16(A[s], B0[s], acc0, 0, 0, 0);
      acc1 = __builtin_amdgcn_mfma_f32_16x16x32_bf16(A[s], B1[s], acc1, 0, 0, 0);
    }

    // z = acc + Zx (own cols), then exchange with lane^8 to gather 4 gates
    float t0[4], t1[4], ot0[4], ot1[4];
    #pragma unroll
    for (int i = 0; i < 4; ++i) { t0[i] = acc0[i] + zc0[i]; t1[i] = acc1[i] + zc1[i]; }
    #pragma unroll
    for (int i = 0; i < 4; ++i) {
      ot0[i] = __shfl_xor(t0[i], 8, 64);
      ot1[i] = __shfl_xor(t1[i], 8, 64);
    }
    float hh[2];
    #pragma unroll
    for (int u = 0; u < 2; ++u) {
      const int i = i0 + u;
      float zf = (q < 8) ? t0[i] : ot0[i];
      float zc = (q < 8) ? ot0[i] : t0[i];
      float zi = (q < 8) ? t1[i] : ot1[i];
      float zo = (q < 8) ? ot1[i] : t1[i];
      float fg = sigm(zf), ig = sigm(zi), og = sigm(zo);
      float Ct = tanh_f(zc);
      float& cr = u ? c1r : c0r;
      cr = fg * cr + ig * Ct;
      hh[u] = og * tanh_f(cr);
    }

    // store h: wave's 16x8 tile is ONE contiguous 256 B block (R7)
    {
      unsigned short hb0 = f2bf(hh[0]), hb1 = f2bf(hh[1]);
      unsigned o0 = (unsigned)(unsigned short)__shfl_xor((int)hb0, 1, 64);
      unsigned o1 = (unsigned)(unsigned short)__shfl_xor((int)hb1, 1, 64);
      if ((q & 1) == 0) {
        const size_t base = (size_t)(st + 1) * kHS + (size_t)cg * 512 +
                            w * 128 + (lg * 4 + i0) * 8 + jj;
        __hip_atomic_store((unsigned*)&hsx[base], ((unsigned)hb0) | (o0 << 16),
                           __ATOMIC_RELAXED, __HIP_MEMORY_SCOPE_AGENT);
        __hip_atomic_store((unsigned*)&hsx[base + 8], ((unsigned)hb1) | (o1 << 16),
                           __ATOMIC_RELAXED, __HIP_MEMORY_SCOPE_AGENT);
      }
      if (st == kL - 1) {
        dout[kOutSz + cidx] = hh[0];
        dout[kOutSz + cidx + 512] = hh[1];
        dout[kOutSz + (size_t)kN * kDH + cidx] = c0r;
        dout[kOutSz + (size_t)kN * kDH + cidx + 512] = c1r;
      }
    }

    // drain (per-wave) -> barrier (all 8 waves drained) -> single publish
    asm volatile("s_waitcnt vmcnt(0)" ::: "memory");
    __syncthreads();
    if (tid == 0)
      __hip_atomic_store(&flags[bi * kFP], (unsigned)(st + 1), __ATOMIC_RELAXED,
                         __HIP_MEMORY_SCOPE_AGENT);

    if (t + 1 < kT) {
      #pragma unroll
      for (int i = 0; i < 4; ++i) { zc0[i] = zn0[i]; zc1[i] = zn1[i]; }
    }
  }

  cbuf[cidx] = c0r;
  cbuf[cidx + 512] = c1r;
}

// ---------------------------------------------------------------- gemm_out
__global__ __launch_bounds__(256) void gemm_out_kernel(
    const unsigned short* __restrict__ Hs,   // hsx + 32768: h_1.. in chunked layout
    const unsigned short* __restrict__ WoT,  // [512][512] bf16 (B^T)
    const float* __restrict__ bout,
    float* __restrict__ out)                 // [32768][512] fp32
{
  __shared__ unsigned short Ash[128][40];
  __shared__ unsigned short Bsh[128][40];
  const int row0 = blockIdx.x * 128, col0 = blockIdx.y * 128;
  const int tid = threadIdx.x;
  const int lane = tid & 63, wave = tid >> 6;
  const int wr = wave >> 1, wc = wave & 1;
  const int m16 = lane & 15, kg = (lane >> 4) * 8;

  f32x4 acc[4][4] = {};

  for (int k0 = 0; k0 < 512; k0 += 32) {
    __syncthreads();
    #pragma unroll
    for (int i = 0; i < 2; ++i) {
      int idx = i * 256 + tid;
      int r = idx >> 2, kq = idx & 3;
      int grow = row0 + r;               // h row: t*64 + n  (t = step-1)
      size_t src = (size_t)(grow >> 6) * kHS + (size_t)((k0 >> 3) + kq) * 512 +
                   ((grow >> 4) & 3) * 128 + (grow & 15) * 8;
      *(uint4*)&Ash[r][kq * 8] = *(const uint4*)&Hs[src];
    }
    #pragma unroll
    for (int i = 0; i < 2; ++i) {
      int idx = i * 256 + tid;
      int c = idx >> 2, kq = idx & 3;
      *(uint4*)&Bsh[c][kq * 8] =
          *(const uint4*)&WoT[(size_t)(col0 + c) * 512 + k0 + kq * 8];
    }
    __syncthreads();
    bf16x8 fa[4], fb[4];
    #pragma unroll
    for (int mi = 0; mi < 4; ++mi) fa[mi] = *(const bf16x8*)&Ash[wr*64 + mi*16 + m16][kg];
    #pragma unroll
    for (int ni = 0; ni < 4; ++ni) fb[ni] = *(const bf16x8*)&Bsh[wc*64 + ni*16 + m16][kg];
    #pragma unroll
    for (int mi = 0; mi < 4; ++mi)
      #pragma unroll
      for (int ni = 0; ni < 4; ++ni)
        acc[mi][ni] = __builtin_amdgcn_mfma_f32_16x16x32_bf16(fa[mi], fb[ni], acc[mi][ni], 0, 0, 0);
  }
  const int rg = (lane >> 4) * 4;
  #pragma unroll
  for (int ni = 0; ni < 4; ++ni) {
    int col = col0 + wc*64 + ni*16 + m16;
    float bb = bout[col];
    #pragma unroll
    for (int mi = 0; mi < 4; ++mi)
      #pragma unroll
      for (int r = 0; r < 4; ++r)
        out[(size_t)(row0 + wr*64 + mi*16 + rg + r) * 512 + col] = acc[mi][ni][r] + bb;
  }
}

// ---------------------------------------------------------------- launch
extern "C" void kernel_launch(void* const* d_in, const int* in_sizes, int n_in,
                              void* d_out, int out_size, void* d_ws, size_t ws_size,
                              hipStream_t stream) {
  (void)in_sizes; (void)n_in; (void)out_size; (void)ws_size;
  const float* x    = (const float*)d_in[0];
  const float* h0   = (const float*)d_in[1];
  const float* c0   = (const float*)d_in[2];
  const float* Wf   = (const float*)d_in[3];
  const float* bf_  = (const float*)d_in[4];
  const float* Wc   = (const float*)d_in[5];
  const float* bc_  = (const float*)d_in[6];
  const float* Wi_  = (const float*)d_in[7];
  const float* bi_  = (const float*)d_in[8];
  const float* Wo   = (const float*)d_in[9];
  const float* bo_  = (const float*)d_in[10];
  const float* Wout = (const float*)d_in[11];
  const float* bout = (const float*)d_in[12];
  float* out = (float*)d_out;

  char* ws = (char*)d_ws;
  size_t off = 0;
  auto alloc = [&](size_t bytes) -> void* {
    void* p = ws + off;
    off += (bytes + 255) & ~(size_t)255;
    return p;
  };
  float*          ZxA = (float*)alloc((size_t)kT * kN * kG * 4);                 // 16 MB
  float*          ZxB = (float*)alloc((size_t)kT * kN * kG * 4);                 // 16 MB
  unsigned short* hsx = (unsigned short*)alloc((size_t)(kL + 1) * kN * kDH * 2); // 33.6 MB
  unsigned short* WxT = (unsigned short*)alloc((size_t)kG * 512 * 2);            // 2 MB
  unsigned short* WoT = (unsigned short*)alloc((size_t)512 * 512 * 2);           // 0.5 MB
  unsigned short* WhB = (unsigned short*)alloc((size_t)64 * 32 * 512 * 2);       // 2 MB
  float*          bg  = (float*)alloc((size_t)kG * 4);
  float*          cbf = (float*)alloc((size_t)kN * kDH * 4);
  unsigned int*   flg = (unsigned int*)alloc((size_t)kRB * kFP * 4);             // 2 KB

  prep_kernel<<<1024, 256, 0, stream>>>(Wf, Wc, Wi_, Wo, bf_, bc_, bi_, bo_,
                                        Wout, h0, c0, WxT, WoT, WhB, bg, hsx, cbf, flg);
  // chunk 0's Zx
  gemm_x_kernel<<<dim3(16, 16), 256, 0, stream>>>(x, WxT, bg, ZxA);
  for (int c = 0; c < kChunks; ++c) {
    float* Zxcur = (c & 1) ? ZxB : ZxA;
    float* Zxnxt = (c & 1) ? ZxA : ZxB;
    const float* xnext = (c + 1 < kChunks)
        ? x + (size_t)(c + 1) * kT * kN * kDIN : nullptr;
    lstm_fused_kernel<<<128, 512, 0, stream>>>(
        WhB, Zxcur, hsx, cbf, c * kT, flg, out, xnext, WxT, bg, Zxnxt);
  }
  gemm_out_kernel<<<dim3(256, 4), 256, 0, stream>>>(
      hsx + (size_t)kN * kDH, WoT, bout, out);
}

// Round 13
// 1785.063 us; speedup vs baseline: 1.2815x; 1.2815x over previous
//
#include <hip/hip_runtime.h>

typedef float  f32x4  __attribute__((ext_vector_type(4)));
typedef short  bf16x8 __attribute__((ext_vector_type(8)));

#define DEVI static __device__ __forceinline__

namespace {
constexpr int kL   = 512;
constexpr int kN   = 64;
constexpr int kDH  = 512;
constexpr int kDIN = 512;
constexpr int kG   = 2048;            // 4*kDH
constexpr int kT   = 32;              // timesteps per chunk
constexpr int kChunks = kL / kT;      // 16
constexpr int kHS  = kN * kDH;        // 32768 elements per step slice
constexpr int kFP = 16;               // flag padding: 1 flag per 64B line
constexpr size_t kOutSz = (size_t)kL * kN * kDIN;  // 16,777,216 floats
}

// hsx layout (bf16): [t][chunk=c/8][w=n/16][n%16][c%8]  (R7 win)
// flags: one per 64B line, wave0-poll + block publish-after-drain (R8 win)
// Zx layout: [cg][t][lane256][8], 32B contiguous per lane (R10 win)
// B-fragments: preloaded to 128 VGPRs once (R10 win)
// R13: sub-gated pipelined begin gate. A[s] consumes chunk 4s+lg, so the
//   64-chunk gate splits into 4 groups of 16 (group g = chunks 16g..16g+15,
//   = A[4g..4g+3]). Wave 0 polls the same single coalesced 64-flag load,
//   classifies ready groups via ballot, publishes per-group LDS tokens;
//   waves 1-3 spin locally on tokens. Each wave issues group-g A-loads as
//   soon as group g is ready -> early loads overlap late producers.

DEVI unsigned short f2bf(float f) {
  union { float f; unsigned u; } v; v.f = f;
  unsigned r = v.u + 0x7FFFu + ((v.u >> 16) & 1u);   // RNE
  return (unsigned short)(r >> 16);
}
DEVI float sigm(float z) { return 1.f / (1.f + __expf(-z)); }
DEVI float tanh_f(float z) { return 2.f / (1.f + __expf(-2.f * z)) - 1.f; }

// ---------------------------------------------------------------- prep
__global__ void prep_kernel(
    const float* __restrict__ Wf, const float* __restrict__ Wc,
    const float* __restrict__ Wi, const float* __restrict__ Wo,
    const float* __restrict__ bf, const float* __restrict__ bc,
    const float* __restrict__ bi, const float* __restrict__ bo,
    const float* __restrict__ Wout,
    const float* __restrict__ h0, const float* __restrict__ c0,
    unsigned short* __restrict__ WxT, unsigned short* __restrict__ WoT,
    unsigned short* __restrict__ WhB, float* __restrict__ bg,
    unsigned short* __restrict__ hsx, float* __restrict__ cbuf,
    unsigned int* __restrict__ flags)
{
  const int gid = blockIdx.x * blockDim.x + threadIdx.x;
  const int stride = gridDim.x * blockDim.x;
  const float* Wg[4]  = {Wf, Wc, Wi, Wo};
  const float* bgs[4] = {bf, bc, bi, bo};

  for (int i = gid; i < 64 * kFP; i += stride) flags[i] = 0u;

  for (int i = gid; i < kG * 512; i += stride) {
    int k = i >> 11, g = i & 2047;
    WxT[(size_t)g * 512 + k] = f2bf(Wg[g >> 9][(size_t)k * 512 + (g & 511)]);
  }
  for (int i = gid; i < 512 * 512; i += stride) {
    int k = i >> 9, c = i & 511;
    WoT[(size_t)c * 512 + k] = f2bf(Wout[(size_t)k * 512 + c]);
  }
  // WhB: i = k*1024 + gate*512 + hcol  -> coalesced source reads
  for (int i = gid; i < 4 * 512 * 512; i += stride) {
    int hcol = i & 511;
    int gate = (i >> 9) & 3;
    int k    = i >> 11;
    int cg = hcol >> 3, jj = hcol & 7;
    int n  = gate * 8 + jj;
    int kblk = k >> 3, kin = k & 7;
    size_t dst = ((size_t)cg * 32 + n) * 512 + (((kblk ^ (n & 7)) << 3) | kin);
    WhB[dst] = f2bf(Wg[gate][(size_t)(512 + k) * 512 + hcol]);
  }
  for (int i = gid; i < kG; i += stride) bg[i] = bgs[i >> 9][i & 511];
  for (int i = gid; i < kN * kDH; i += stride) {
    int n = i >> 9, c = i & 511;   // h0[n][c]
    hsx[((size_t)(c >> 3)) * 512 + ((n >> 4) * 128) + ((n & 15) * 8) + (c & 7)]
        = f2bf(h0[i]);             // hsx[0] in chunked layout
    cbuf[i] = c0[i];
  }
}

// Shared-memory overlay for the fused kernel's two roles.
struct SMem {
  union {
    unsigned short WT[32 * 512];                                   // rec: 32 KB
    struct { unsigned short Ash[128][40]; unsigned short Bsh[128][40]; } g;  // 20 KB
  };
};

// ---------------------------------------------------------------- gemm_x body
// z[row][col] with col = gate*512 + cg*8 + jj; n = gate*8+jj; q=n&15, half=n>>4.
// Write lane-swizzled Zx: [(cg*32 + t)*256 + (w*64+lg*16+q)]*8 + i*2 + half.
DEVI void gemm_x_tile(SMem& sm, const float* __restrict__ X,
                      const unsigned short* __restrict__ WxT,
                      const float* __restrict__ bg,
                      float* __restrict__ Zx2, int row0, int col0, int tid)
{
  const int lane = tid & 63, wave = tid >> 6;
  const int wr = wave >> 1, wc = wave & 1;
  const int m16 = lane & 15, kg = (lane >> 4) * 8;

  f32x4 acc[4][4] = {};

  for (int k0 = 0; k0 < 512; k0 += 32) {
    __syncthreads();
    #pragma unroll
    for (int i = 0; i < 4; ++i) {
      int idx = i * 256 + tid;
      int r = idx >> 3, kq = idx & 7;
      float4 v = *(const float4*)&X[(size_t)(row0 + r) * 512 + k0 + kq * 4];
      unsigned short* dst = &sm.g.Ash[r][kq * 4];
      dst[0] = f2bf(v.x); dst[1] = f2bf(v.y); dst[2] = f2bf(v.z); dst[3] = f2bf(v.w);
    }
    #pragma unroll
    for (int i = 0; i < 2; ++i) {
      int idx = i * 256 + tid;
      int c = idx >> 2, kq = idx & 3;
      *(uint4*)&sm.g.Bsh[c][kq * 8] =
          *(const uint4*)&WxT[(size_t)(col0 + c) * 512 + k0 + kq * 8];
    }
    __syncthreads();
    bf16x8 fa[4], fb[4];
    #pragma unroll
    for (int mi = 0; mi < 4; ++mi) fa[mi] = *(const bf16x8*)&sm.g.Ash[wr*64 + mi*16 + m16][kg];
    #pragma unroll
    for (int ni = 0; ni < 4; ++ni) fb[ni] = *(const bf16x8*)&sm.g.Bsh[wc*64 + ni*16 + m16][kg];
    #pragma unroll
    for (int mi = 0; mi < 4; ++mi)
      #pragma unroll
      for (int ni = 0; ni < 4; ++ni)
        acc[mi][ni] = __builtin_amdgcn_mfma_f32_16x16x32_bf16(fa[mi], fb[ni], acc[mi][ni], 0, 0, 0);
  }
  const int rg = (lane >> 4) * 4;
  #pragma unroll
  for (int ni = 0; ni < 4; ++ni) {
    int col = col0 + wc*64 + ni*16 + m16;
    float bb = bg[col];
    int gate = col >> 9, hcol = col & 511;
    int cg = hcol >> 3, n = gate * 8 + (hcol & 7);
    int qn = n & 15, half = n >> 4;
    #pragma unroll
    for (int mi = 0; mi < 4; ++mi)
      #pragma unroll
      for (int r = 0; r < 4; ++r) {
        int row = row0 + wr*64 + mi*16 + rg + r;
        int t = row >> 6, b = row & 63;
        int wv = b >> 4, lgv = (b >> 2) & 3, iv = b & 3;
        Zx2[((size_t)(cg * 32 + t) * 256 + (wv * 64 + lgv * 16 + qn)) * 8 +
            iv * 2 + half] = acc[mi][ni][r] + bb;
      }
  }
}

// ---------------------------------------------------------------- gemm_x (standalone, chunk 0)
__global__ __launch_bounds__(256) void gemm_x_kernel(
    const float* __restrict__ X, const unsigned short* __restrict__ WxT,
    const float* __restrict__ bg, float* __restrict__ Zx2)
{
  __shared__ SMem sm;
  gemm_x_tile(sm, X, WxT, bg, Zx2, blockIdx.x * 128, blockIdx.y * 128, threadIdx.x);
}

// ---------------------------------------------------------------- fused: rec (blk 0..63) + next-chunk gemm_x (blk 64..255)
__global__ __launch_bounds__(256, 1) void lstm_fused_kernel(
    const unsigned short* __restrict__ WhB,  // [64][32][512] bf16 swizzled
    const float* __restrict__ Zxcur,         // [64][32][256][8] lane-swizzled
    unsigned short* __restrict__ hsx,        // [513][...] bf16, chunked layout
    float* __restrict__ cbuf,                // [64][512] fp32
    int step0,
    unsigned int* __restrict__ flags,        // [64*kFP], flag at cg*kFP
    float* __restrict__ dout,
    const float* __restrict__ Xnext,         // next chunk x (null on last)
    const unsigned short* __restrict__ WxT,
    const float* __restrict__ bg,
    float* __restrict__ Zxnext)              // next chunk Zx buffer
{
  __shared__ SMem sm;
  __shared__ unsigned tok[4];                // per-group step tokens (rec role)
  const int tid = threadIdx.x;

  if (blockIdx.x >= 64) {
    // ---------------- gemm role: compute Zx for chunk c+1 ----------------
    if (Xnext == nullptr) return;
    for (int tile = (int)blockIdx.x - 64; tile < 256; tile += 192) {
      gemm_x_tile(sm, Xnext, WxT, bg, Zxnext, (tile >> 4) * 128, (tile & 15) * 128, tid);
      __syncthreads();
    }
    return;
  }

  // ---------------- rec role ----------------
  const int cg = blockIdx.x;
  const int j0 = cg * 8;
  const int w   = tid >> 6;           // wave 0..3 -> batch rows w*16..+16
  const int l   = tid & 63;
  const int q   = l & 15;             // n-col within frag
  const int lg  = l >> 4;             // k-group
  const int jj  = q & 7;
  const int i0  = (q < 8) ? 0 : 2;    // acc rows this lane finishes

  // one-time: W slice -> LDS (linear copy; swizzle pre-applied by prep)
  {
    const uint4* wsrc = (const uint4*)(WhB + (size_t)cg * 32 * 512);
    uint4* wdst = (uint4*)sm.WT;
    #pragma unroll
    for (int i = 0; i < 8; ++i) wdst[i * 256 + tid] = wsrc[i * 256 + tid];
  }
  if (tid < 4) tok[tid] = 0u;
  const size_t cidx = (size_t)(w * 16 + lg * 4 + i0) * 512 + j0 + jj;
  float c0r = cbuf[cidx];
  float c1r = cbuf[cidx + 512];
  __syncthreads();

  // one-time: preload ALL B fragments into registers (W is step-invariant).
  bf16x8 B0[16], B1[16];
  #pragma unroll
  for (int s = 0; s < 16; ++s) {
    const int kb = 4 * s + lg;
    B0[s] = *(const bf16x8*)&sm.WT[(size_t)q * 512 + ((kb ^ jj) << 3)];
    B1[s] = *(const bf16x8*)&sm.WT[(size_t)(16 + q) * 512 + ((kb ^ jj) << 3)];
  }

  // Zx base for this lane: 8 floats per step, 2048 floats per step per block
  const float* zbase = Zxcur + (size_t)cg * 32 * 2048 + (size_t)tid * 8;

  // Zx for t=0 (2 x f32x4, 32B contiguous per lane)
  float zc0[4], zc1[4];
  {
    f32x4 a = *(const f32x4*)zbase;
    f32x4 b = *(const f32x4*)(zbase + 4);
    zc0[0] = a[0]; zc1[0] = a[1]; zc0[1] = a[2]; zc1[1] = a[3];
    zc0[2] = b[0]; zc1[2] = b[1]; zc0[3] = b[2]; zc1[3] = b[3];
  }

#define LOADG(g)                                                      \
  do {                                                                \
    A[4*(g)+0] = *(const bf16x8*)(hrow + 2048 * (4*(g)+0));           \
    A[4*(g)+1] = *(const bf16x8*)(hrow + 2048 * (4*(g)+1));           \
    A[4*(g)+2] = *(const bf16x8*)(hrow + 2048 * (4*(g)+2));           \
    A[4*(g)+3] = *(const bf16x8*)(hrow + 2048 * (4*(g)+3));           \
  } while (0)

  for (int t = 0; t < kT; ++t) {
    const int st = step0 + t;

    // A-frags from chunked layout: A[s] = row w*16+q, chunk 4s+lg.
    const unsigned short* hrow =
        hsx + (size_t)st * kHS + (size_t)lg * 512 + w * 128 + q * 8;
    bf16x8 A[16];

    if (t > 0) {
      if (w == 0) {
        // wave 0: single coalesced 64-flag poll (lane l <-> chunk l), ballot-
        // classified into 4 ready groups; publish LDS tokens; issue group
        // loads as each group becomes ready (early loads overlap late
        // producers).
        unsigned rdy = 0;
        auto refresh = [&]() {
          int fv = (int)__hip_atomic_load(&flags[l * kFP], __ATOMIC_RELAXED,
                                          __HIP_MEMORY_SCOPE_AGENT);
          unsigned long long bl = __ballot(fv >= st);
          unsigned nr = 0;
          if (((bl >>  0) & 0xFFFFull) == 0xFFFFull) nr |= 1u;
          if (((bl >> 16) & 0xFFFFull) == 0xFFFFull) nr |= 2u;
          if (((bl >> 32) & 0xFFFFull) == 0xFFFFull) nr |= 4u;
          if (((bl >> 48) & 0xFFFFull) == 0xFFFFull) nr |= 8u;
          unsigned nw = nr & ~rdy;
          if (nw && l == 0) {
            if (nw & 1u) __hip_atomic_store(&tok[0], (unsigned)st,
                             __ATOMIC_RELAXED, __HIP_MEMORY_SCOPE_WORKGROUP);
            if (nw & 2u) __hip_atomic_store(&tok[1], (unsigned)st,
                             __ATOMIC_RELAXED, __HIP_MEMORY_SCOPE_WORKGROUP);
            if (nw & 4u) __hip_atomic_store(&tok[2], (unsigned)st,
                             __ATOMIC_RELAXED, __HIP_MEMORY_SCOPE_WORKGROUP);
            if (nw & 8u) __hip_atomic_store(&tok[3], (unsigned)st,
                             __ATOMIC_RELAXED, __HIP_MEMORY_SCOPE_WORKGROUP);
          }
          rdy |= nr;
        };
        while (!(rdy & 1u)) refresh();
        asm volatile("" ::: "memory");
        LOADG(0);
        while (!(rdy & 2u)) refresh();
        asm volatile("" ::: "memory");
        LOADG(1);
        while (!(rdy & 4u)) refresh();
        asm volatile("" ::: "memory");
        LOADG(2);
        while (!(rdy & 8u)) refresh();
        asm volatile("" ::: "memory");
        LOADG(3);
      } else {
        // waves 1-3: spin on LDS tokens (no fabric traffic), issue per group
        while (__hip_atomic_load(&tok[0], __ATOMIC_RELAXED,
                                 __HIP_MEMORY_SCOPE_WORKGROUP) < (unsigned)st) {}
        asm volatile("" ::: "memory");
        LOADG(0);
        while (__hip_atomic_load(&tok[1], __ATOMIC_RELAXED,
                                 __HIP_MEMORY_SCOPE_WORKGROUP) < (unsigned)st) {}
        asm volatile("" ::: "memory");
        LOADG(1);
        while (__hip_atomic_load(&tok[2], __ATOMIC_RELAXED,
                                 __HIP_MEMORY_SCOPE_WORKGROUP) < (unsigned)st) {}
        asm volatile("" ::: "memory");
        LOADG(2);
        while (__hip_atomic_load(&tok[3], __ATOMIC_RELAXED,
                                 __HIP_MEMORY_SCOPE_WORKGROUP) < (unsigned)st) {}
        asm volatile("" ::: "memory");
        LOADG(3);
      }
    } else {
      LOADG(0); LOADG(1); LOADG(2); LOADG(3);
    }

    // Zx prefetch for t+1 issued BEFORE MFMA: completes under compute.
    float zn0[4], zn1[4];
    if (t + 1 < kT) {
      const float* zb = zbase + (size_t)(t + 1) * 2048;
      f32x4 a = *(const f32x4*)zb;
      f32x4 b = *(const f32x4*)(zb + 4);
      zn0[0] = a[0]; zn1[0] = a[1]; zn0[1] = a[2]; zn1[1] = a[3];
      zn0[2] = b[0]; zn1[2] = b[1]; zn0[3] = b[2]; zn1[3] = b[3];
    }

    // MFMA: 16 ksteps x 2 n-frags, B from registers (no LDS in loop)
    f32x4 acc0 = {}, acc1 = {};
    #pragma unroll
    for (int s = 0; s < 16; ++s) {
      acc0 = __builtin_amdgcn_mfma_f32_16x16x32_bf16(A[s], B0[s], acc0, 0, 0, 0);
      acc1 = __builtin_amdgcn_mfma_f32_16x16x32_bf16(A[s], B1[s], acc1, 0, 0, 0);
    }

    // z = acc + Zx (own cols), then exchange with lane^8 to gather 4 gates
    float t0[4], t1[4], ot0[4], ot1[4];
    #pragma unroll
    for (int i = 0; i < 4; ++i) { t0[i] = acc0[i] + zc0[i]; t1[i] = acc1[i] + zc1[i]; }
    #pragma unroll
    for (int i = 0; i < 4; ++i) {
      ot0[i] = __shfl_xor(t0[i], 8, 64);
      ot1[i] = __shfl_xor(t1[i], 8, 64);
    }
    float hh[2];
    #pragma unroll
    for (int u = 0; u < 2; ++u) {
      const int i = i0 + u;
      float zf = (q < 8) ? t0[i] : ot0[i];
      float zc = (q < 8) ? ot0[i] : t0[i];
      float zi = (q < 8) ? t1[i] : ot1[i];
      float zo = (q < 8) ? ot1[i] : t1[i];
      float fg = sigm(zf), ig = sigm(zi), og = sigm(zo);
      float Ct = tanh_f(zc);
      float& cr = u ? c1r : c0r;
      cr = fg * cr + ig * Ct;
      hh[u] = og * tanh_f(cr);
    }

    // store h: wave's 16x8 tile is ONE contiguous 256 B block (R7)
    {
      unsigned short hb0 = f2bf(hh[0]), hb1 = f2bf(hh[1]);
      unsigned o0 = (unsigned)(unsigned short)__shfl_xor((int)hb0, 1, 64);
      unsigned o1 = (unsigned)(unsigned short)__shfl_xor((int)hb1, 1, 64);
      if ((q & 1) == 0) {
        const size_t base = (size_t)(st + 1) * kHS + (size_t)cg * 512 +
                            w * 128 + (lg * 4 + i0) * 8 + jj;
        __hip_atomic_store((unsigned*)&hsx[base], ((unsigned)hb0) | (o0 << 16),
                           __ATOMIC_RELAXED, __HIP_MEMORY_SCOPE_AGENT);
        __hip_atomic_store((unsigned*)&hsx[base + 8], ((unsigned)hb1) | (o1 << 16),
                           __ATOMIC_RELAXED, __HIP_MEMORY_SCOPE_AGENT);
      }
      if (st == kL - 1) {
        dout[kOutSz + cidx] = hh[0];
        dout[kOutSz + cidx + 512] = hh[1];
        dout[kOutSz + (size_t)kN * kDH + cidx] = c0r;
        dout[kOutSz + (size_t)kN * kDH + cidx + 512] = c1r;
      }
    }

    // drain h stores, then publish flag (own 64B line)  [R8 protocol, frozen]
    asm volatile("s_waitcnt vmcnt(0)" ::: "memory");
    __syncthreads();
    if (tid == 0)
      __hip_atomic_store(&flags[cg * kFP], (unsigned)(st + 1), __ATOMIC_RELAXED,
                         __HIP_MEMORY_SCOPE_AGENT);

    if (t + 1 < kT) {
      #pragma unroll
      for (int i = 0; i < 4; ++i) { zc0[i] = zn0[i]; zc1[i] = zn1[i]; }
    }
  }
#undef LOADG

  cbuf[cidx] = c0r;
  cbuf[cidx + 512] = c1r;
}

// ---------------------------------------------------------------- gemm_out
__global__ __launch_bounds__(256) void gemm_out_kernel(
    const unsigned short* __restrict__ Hs,   // hsx + 32768: h_1.. in chunked layout
    const unsigned short* __restrict__ WoT,  // [512][512] bf16 (B^T)
    const float* __restrict__ bout,
    float* __restrict__ out)                 // [32768][512] fp32
{
  __shared__ unsigned short Ash[128][40];
  __shared__ unsigned short Bsh[128][40];
  const int row0 = blockIdx.x * 128, col0 = blockIdx.y * 128;
  const int tid = threadIdx.x;
  const int lane = tid & 63, wave = tid >> 6;
  const int wr = wave >> 1, wc = wave & 1;
  const int m16 = lane & 15, kg = (lane >> 4) * 8;

  f32x4 acc[4][4] = {};

  for (int k0 = 0; k0 < 512; k0 += 32) {
    __syncthreads();
    #pragma unroll
    for (int i = 0; i < 2; ++i) {
      int idx = i * 256 + tid;
      int r = idx >> 2, kq = idx & 3;
      int grow = row0 + r;               // h row: t*64 + n  (t = step-1)
      size_t src = (size_t)(grow >> 6) * kHS + (size_t)((k0 >> 3) + kq) * 512 +
                   ((grow >> 4) & 3) * 128 + (grow & 15) * 8;
      *(uint4*)&Ash[r][kq * 8] = *(const uint4*)&Hs[src];
    }
    #pragma unroll
    for (int i = 0; i < 2; ++i) {
      int idx = i * 256 + tid;
      int c = idx >> 2, kq = idx & 3;
      *(uint4*)&Bsh[c][kq * 8] =
          *(const uint4*)&WoT[(size_t)(col0 + c) * 512 + k0 + kq * 8];
    }
    __syncthreads();
    bf16x8 fa[4], fb[4];
    #pragma unroll
    for (int mi = 0; mi < 4; ++mi) fa[mi] = *(const bf16x8*)&Ash[wr*64 + mi*16 + m16][kg];
    #pragma unroll
    for (int ni = 0; ni < 4; ++ni) fb[ni] = *(const bf16x8*)&Bsh[wc*64 + ni*16 + m16][kg];
    #pragma unroll
    for (int mi = 0; mi < 4; ++mi)
      #pragma unroll
      for (int ni = 0; ni < 4; ++ni)
        acc[mi][ni] = __builtin_amdgcn_mfma_f32_16x16x32_bf16(fa[mi], fb[ni], acc[mi][ni], 0, 0, 0);
  }
  const int rg = (lane >> 4) * 4;
  #pragma unroll
  for (int ni = 0; ni < 4; ++ni) {
    int col = col0 + wc*64 + ni*16 + m16;
    float bb = bout[col];
    #pragma unroll
    for (int mi = 0; mi < 4; ++mi)
      #pragma unroll
      for (int r = 0; r < 4; ++r)
        out[(size_t)(row0 + wr*64 + mi*16 + rg + r) * 512 + col] = acc[mi][ni][r] + bb;
  }
}

// ---------------------------------------------------------------- launch
extern "C" void kernel_launch(void* const* d_in, const int* in_sizes, int n_in,
                              void* d_out, int out_size, void* d_ws, size_t ws_size,
                              hipStream_t stream) {
  (void)in_sizes; (void)n_in; (void)out_size; (void)ws_size;
  const float* x    = (const float*)d_in[0];
  const float* h0   = (const float*)d_in[1];
  const float* c0   = (const float*)d_in[2];
  const float* Wf   = (const float*)d_in[3];
  const float* bf_  = (const float*)d_in[4];
  const float* Wc   = (const float*)d_in[5];
  const float* bc_  = (const float*)d_in[6];
  const float* Wi_  = (const float*)d_in[7];
  const float* bi_  = (const float*)d_in[8];
  const float* Wo   = (const float*)d_in[9];
  const float* bo_  = (const float*)d_in[10];
  const float* Wout = (const float*)d_in[11];
  const float* bout = (const float*)d_in[12];
  float* out = (float*)d_out;

  char* ws = (char*)d_ws;
  size_t off = 0;
  auto alloc = [&](size_t bytes) -> void* {
    void* p = ws + off;
    off += (bytes + 255) & ~(size_t)255;
    return p;
  };
  float*          ZxA = (float*)alloc((size_t)kT * kN * kG * 4);                 // 16 MB
  float*          ZxB = (float*)alloc((size_t)kT * kN * kG * 4);                 // 16 MB
  unsigned short* hsx = (unsigned short*)alloc((size_t)(kL + 1) * kN * kDH * 2); // 33.6 MB
  unsigned short* WxT = (unsigned short*)alloc((size_t)kG * 512 * 2);            // 2 MB
  unsigned short* WoT = (unsigned short*)alloc((size_t)512 * 512 * 2);           // 0.5 MB
  unsigned short* WhB = (unsigned short*)alloc((size_t)64 * 32 * 512 * 2);       // 2 MB
  float*          bg  = (float*)alloc((size_t)kG * 4);
  float*          cbf = (float*)alloc((size_t)kN * kDH * 4);
  unsigned int*   flg = (unsigned int*)alloc((size_t)64 * kFP * 4);              // 4 KB

  prep_kernel<<<1024, 256, 0, stream>>>(Wf, Wc, Wi_, Wo, bf_, bc_, bi_, bo_,
                                        Wout, h0, c0, WxT, WoT, WhB, bg, hsx, cbf, flg);
  // chunk 0's Zx
  gemm_x_kernel<<<dim3(16, 16), 256, 0, stream>>>(x, WxT, bg, ZxA);
  for (int c = 0; c < kChunks; ++c) {
    float* Zxcur = (c & 1) ? ZxB : ZxA;
    float* Zxnxt = (c & 1) ? ZxA : ZxB;
    const float* xnext = (c + 1 < kChunks)
        ? x + (size_t)(c + 1) * kT * kN * kDIN : nullptr;
    lstm_fused_kernel<<<256, 256, 0, stream>>>(
        WhB, Zxcur, hsx, cbf, c * kT, flg, out, xnext, WxT, bg, Zxnxt);
  }
  gemm_out_kernel<<<dim3(256, 4), 256, 0, stream>>>(
      hsx + (size_t)kN * kDH, WoT, bout, out);
}

// Round 14
// 1726.803 us; speedup vs baseline: 1.3248x; 1.0337x over previous
//
#include <hip/hip_runtime.h>

typedef float  f32x4  __attribute__((ext_vector_type(4)));
typedef short  bf16x8 __attribute__((ext_vector_type(8)));

#define DEVI static __device__ __forceinline__

namespace {
constexpr int kL   = 512;
constexpr int kN   = 64;
constexpr int kDH  = 512;
constexpr int kDIN = 512;
constexpr int kG   = 2048;            // 4*kDH
constexpr int kT   = 32;              // timesteps per chunk
constexpr int kChunks = kL / kT;      // 16
constexpr int kHS  = kN * kDH;        // 32768 elements per step slice
constexpr int kFP = 16;               // flag padding: 1 flag per 64B line
constexpr size_t kOutSz = (size_t)kL * kN * kDIN;  // 16,777,216 floats
}

// hsx layout (bf16): [t][chunk=c/8][w=n/16][n%16][c%8]  (R7 win)
// flags: one per 64B line, wave0-poll + barrier + block publish (R8 win)
// Zx layout (R10): [cg][t][lane(256)][8] -> each rec lane's step slice is
//   32B contiguous (2x f32x4); gemm_x epilogue writes this order.
// B-fragments (R10): preloaded to 128 VGPRs once; no in-loop LDS reads.
// R14: exact revert to R10 (best measured); R11/R12/R13 alternatives all
//   flat or worse -> per-step IC all-to-all chain is the structural floor.

DEVI unsigned short f2bf(float f) {
  union { float f; unsigned u; } v; v.f = f;
  unsigned r = v.u + 0x7FFFu + ((v.u >> 16) & 1u);   // RNE
  return (unsigned short)(r >> 16);
}
DEVI float sigm(float z) { return 1.f / (1.f + __expf(-z)); }
DEVI float tanh_f(float z) { return 2.f / (1.f + __expf(-2.f * z)) - 1.f; }

// ---------------------------------------------------------------- prep
__global__ void prep_kernel(
    const float* __restrict__ Wf, const float* __restrict__ Wc,
    const float* __restrict__ Wi, const float* __restrict__ Wo,
    const float* __restrict__ bf, const float* __restrict__ bc,
    const float* __restrict__ bi, const float* __restrict__ bo,
    const float* __restrict__ Wout,
    const float* __restrict__ h0, const float* __restrict__ c0,
    unsigned short* __restrict__ WxT, unsigned short* __restrict__ WoT,
    unsigned short* __restrict__ WhB, float* __restrict__ bg,
    unsigned short* __restrict__ hsx, float* __restrict__ cbuf,
    unsigned int* __restrict__ flags)
{
  const int gid = blockIdx.x * blockDim.x + threadIdx.x;
  const int stride = gridDim.x * blockDim.x;
  const float* Wg[4]  = {Wf, Wc, Wi, Wo};
  const float* bgs[4] = {bf, bc, bi, bo};

  for (int i = gid; i < 64 * kFP; i += stride) flags[i] = 0u;

  for (int i = gid; i < kG * 512; i += stride) {
    int k = i >> 11, g = i & 2047;
    WxT[(size_t)g * 512 + k] = f2bf(Wg[g >> 9][(size_t)k * 512 + (g & 511)]);
  }
  for (int i = gid; i < 512 * 512; i += stride) {
    int k = i >> 9, c = i & 511;
    WoT[(size_t)c * 512 + k] = f2bf(Wout[(size_t)k * 512 + c]);
  }
  // WhB: i = k*1024 + gate*512 + hcol  -> coalesced source reads
  for (int i = gid; i < 4 * 512 * 512; i += stride) {
    int hcol = i & 511;
    int gate = (i >> 9) & 3;
    int k    = i >> 11;
    int cg = hcol >> 3, jj = hcol & 7;
    int n  = gate * 8 + jj;
    int kblk = k >> 3, kin = k & 7;
    size_t dst = ((size_t)cg * 32 + n) * 512 + (((kblk ^ (n & 7)) << 3) | kin);
    WhB[dst] = f2bf(Wg[gate][(size_t)(512 + k) * 512 + hcol]);
  }
  for (int i = gid; i < kG; i += stride) bg[i] = bgs[i >> 9][i & 511];
  for (int i = gid; i < kN * kDH; i += stride) {
    int n = i >> 9, c = i & 511;   // h0[n][c]
    hsx[((size_t)(c >> 3)) * 512 + ((n >> 4) * 128) + ((n & 15) * 8) + (c & 7)]
        = f2bf(h0[i]);             // hsx[0] in chunked layout
    cbuf[i] = c0[i];
  }
}

// Shared-memory overlay for the fused kernel's two roles.
struct SMem {
  union {
    unsigned short WT[32 * 512];                                   // rec: 32 KB
    struct { unsigned short Ash[128][40]; unsigned short Bsh[128][40]; } g;  // 20 KB
  };
};

// ---------------------------------------------------------------- gemm_x body
// z[row][col] with col = gate*512 + cg*8 + jj; n = gate*8+jj; q=n&15, half=n>>4.
// Write to lane-swizzled Zx: [(cg*32 + t)*256 + (w*64+lg*16+q)]*8 + i*2 + half,
// where row = t*64 + w*16 + lg*4 + i.
DEVI void gemm_x_tile(SMem& sm, const float* __restrict__ X,
                      const unsigned short* __restrict__ WxT,
                      const float* __restrict__ bg,
                      float* __restrict__ Zx2, int row0, int col0, int tid)
{
  const int lane = tid & 63, wave = tid >> 6;
  const int wr = wave >> 1, wc = wave & 1;
  const int m16 = lane & 15, kg = (lane >> 4) * 8;

  f32x4 acc[4][4] = {};

  for (int k0 = 0; k0 < 512; k0 += 32) {
    __syncthreads();
    #pragma unroll
    for (int i = 0; i < 4; ++i) {
      int idx = i * 256 + tid;
      int r = idx >> 3, kq = idx & 7;
      float4 v = *(const float4*)&X[(size_t)(row0 + r) * 512 + k0 + kq * 4];
      unsigned short* dst = &sm.g.Ash[r][kq * 4];
      dst[0] = f2bf(v.x); dst[1] = f2bf(v.y); dst[2] = f2bf(v.z); dst[3] = f2bf(v.w);
    }
    #pragma unroll
    for (int i = 0; i < 2; ++i) {
      int idx = i * 256 + tid;
      int c = idx >> 2, kq = idx & 3;
      *(uint4*)&sm.g.Bsh[c][kq * 8] =
          *(const uint4*)&WxT[(size_t)(col0 + c) * 512 + k0 + kq * 8];
    }
    __syncthreads();
    bf16x8 fa[4], fb[4];
    #pragma unroll
    for (int mi = 0; mi < 4; ++mi) fa[mi] = *(const bf16x8*)&sm.g.Ash[wr*64 + mi*16 + m16][kg];
    #pragma unroll
    for (int ni = 0; ni < 4; ++ni) fb[ni] = *(const bf16x8*)&sm.g.Bsh[wc*64 + ni*16 + m16][kg];
    #pragma unroll
    for (int mi = 0; mi < 4; ++mi)
      #pragma unroll
      for (int ni = 0; ni < 4; ++ni)
        acc[mi][ni] = __builtin_amdgcn_mfma_f32_16x16x32_bf16(fa[mi], fb[ni], acc[mi][ni], 0, 0, 0);
  }
  const int rg = (lane >> 4) * 4;
  #pragma unroll
  for (int ni = 0; ni < 4; ++ni) {
    int col = col0 + wc*64 + ni*16 + m16;
    float bb = bg[col];
    int gate = col >> 9, hcol = col & 511;
    int cg = hcol >> 3, n = gate * 8 + (hcol & 7);
    int qn = n & 15, half = n >> 4;
    #pragma unroll
    for (int mi = 0; mi < 4; ++mi)
      #pragma unroll
      for (int r = 0; r < 4; ++r) {
        int row = row0 + wr*64 + mi*16 + rg + r;
        int t = row >> 6, b = row & 63;
        int wv = b >> 4, lgv = (b >> 2) & 3, iv = b & 3;
        Zx2[((size_t)(cg * 32 + t) * 256 + (wv * 64 + lgv * 16 + qn)) * 8 +
            iv * 2 + half] = acc[mi][ni][r] + bb;
      }
  }
}

// ---------------------------------------------------------------- gemm_x (standalone, chunk 0)
__global__ __launch_bounds__(256) void gemm_x_kernel(
    const float* __restrict__ X, const unsigned short* __restrict__ WxT,
    const float* __restrict__ bg, float* __restrict__ Zx2)
{
  __shared__ SMem sm;
  gemm_x_tile(sm, X, WxT, bg, Zx2, blockIdx.x * 128, blockIdx.y * 128, threadIdx.x);
}

// ---------------------------------------------------------------- fused: rec (blk 0..63) + next-chunk gemm_x (blk 64..255)
__global__ __launch_bounds__(256, 1) void lstm_fused_kernel(
    const unsigned short* __restrict__ WhB,  // [64][32][512] bf16 swizzled
    const float* __restrict__ Zxcur,         // [64][32][256][8] lane-swizzled
    unsigned short* __restrict__ hsx,        // [513][...] bf16, chunked layout
    float* __restrict__ cbuf,                // [64][512] fp32
    int step0,
    unsigned int* __restrict__ flags,        // [64*kFP], flag at cg*kFP
    float* __restrict__ dout,
    const float* __restrict__ Xnext,         // next chunk x (null on last)
    const unsigned short* __restrict__ WxT,
    const float* __restrict__ bg,
    float* __restrict__ Zxnext)              // next chunk Zx buffer
{
  __shared__ SMem sm;
  const int tid = threadIdx.x;

  if (blockIdx.x >= 64) {
    // ---------------- gemm role: compute Zx for chunk c+1 ----------------
    if (Xnext == nullptr) return;
    for (int tile = (int)blockIdx.x - 64; tile < 256; tile += 192) {
      gemm_x_tile(sm, Xnext, WxT, bg, Zxnext, (tile >> 4) * 128, (tile & 15) * 128, tid);
      __syncthreads();
    }
    return;
  }

  // ---------------- rec role ----------------
  const int cg = blockIdx.x;
  const int j0 = cg * 8;
  const int w   = tid >> 6;           // wave 0..3 -> batch rows w*16..+16
  const int l   = tid & 63;
  const int q   = l & 15;             // n-col within frag
  const int lg  = l >> 4;             // k-group
  const int jj  = q & 7;
  const int i0  = (q < 8) ? 0 : 2;    // acc rows this lane finishes

  // one-time: W slice -> LDS (linear copy; swizzle pre-applied by prep)
  {
    const uint4* wsrc = (const uint4*)(WhB + (size_t)cg * 32 * 512);
    uint4* wdst = (uint4*)sm.WT;
    #pragma unroll
    for (int i = 0; i < 8; ++i) wdst[i * 256 + tid] = wsrc[i * 256 + tid];
  }
  const size_t cidx = (size_t)(w * 16 + lg * 4 + i0) * 512 + j0 + jj;
  float c0r = cbuf[cidx];
  float c1r = cbuf[cidx + 512];
  __syncthreads();

  // one-time: preload ALL B fragments into registers (W is step-invariant).
  // 32 x bf16x8 = 128 VGPR; static indices only (unrolled) to stay in regs.
  bf16x8 B0[16], B1[16];
  #pragma unroll
  for (int s = 0; s < 16; ++s) {
    const int kb = 4 * s + lg;
    B0[s] = *(const bf16x8*)&sm.WT[(size_t)q * 512 + ((kb ^ jj) << 3)];
    B1[s] = *(const bf16x8*)&sm.WT[(size_t)(16 + q) * 512 + ((kb ^ jj) << 3)];
  }

  // Zx base for this lane: 8 floats per step, 2048 floats per step per block
  const float* zbase = Zxcur + (size_t)cg * 32 * 2048 + (size_t)tid * 8;

  // Zx for t=0 (2 x f32x4, 32B contiguous per lane)
  float zc0[4], zc1[4];
  {
    f32x4 a = *(const f32x4*)zbase;
    f32x4 b = *(const f32x4*)(zbase + 4);
    zc0[0] = a[0]; zc1[0] = a[1]; zc0[1] = a[2]; zc1[1] = a[3];
    zc0[2] = b[0]; zc1[2] = b[1]; zc0[3] = b[2]; zc1[3] = b[3];
  }

  for (int t = 0; t < kT; ++t) {
    const int st = step0 + t;

    // wait for hsx[st] (skip t=0: previous dispatch completed it).
    // Wave 0 polls: lane l watches flags[l*kFP] (64 distinct lines).
    if (t > 0) {
      if (tid < 64) {
        for (;;) {
          int fv = (int)__hip_atomic_load(&flags[l * kFP], __ATOMIC_RELAXED,
                                          __HIP_MEMORY_SCOPE_AGENT);
          if (__all(fv >= st)) break;
        }
      }
      __syncthreads();
    }

    // A-frags from chunked layout: A[s] = row w*16+q, cols 8*(4s+lg)..+7
    const unsigned short* hrow =
        hsx + (size_t)st * kHS + (size_t)lg * 512 + w * 128 + q * 8;
    bf16x8 A[16];
    #pragma unroll
    for (int s = 0; s < 16; ++s) A[s] = *(const bf16x8*)(hrow + 2048 * s);

    // Zx prefetch for t+1 issued BEFORE MFMA: completes under compute.
    float zn0[4], zn1[4];
    if (t + 1 < kT) {
      const float* zb = zbase + (size_t)(t + 1) * 2048;
      f32x4 a = *(const f32x4*)zb;
      f32x4 b = *(const f32x4*)(zb + 4);
      zn0[0] = a[0]; zn1[0] = a[1]; zn0[1] = a[2]; zn1[1] = a[3];
      zn0[2] = b[0]; zn1[2] = b[1]; zn0[3] = b[2]; zn1[3] = b[3];
    }

    // MFMA: 16 ksteps x 2 n-frags, B from registers (no LDS in loop)
    f32x4 acc0 = {}, acc1 = {};
    #pragma unroll
    for (int s = 0; s < 16; ++s) {
      acc0 = __builtin_amdgcn_mfma_f32_16x16x32_bf16(A[s], B0[s], acc0, 0, 0, 0);
      acc1 = __builtin_amdgcn_mfma_f32_16x16x32_bf16(A[s], B1[s], acc1, 0, 0, 0);
    }

    // z = acc + Zx (own cols), then exchange with lane^8 to gather 4 gates
    float t0[4], t1[4], ot0[4], ot1[4];
    #pragma unroll
    for (int i = 0; i < 4; ++i) { t0[i] = acc0[i] + zc0[i]; t1[i] = acc1[i] + zc1[i]; }
    #pragma unroll
    for (int i = 0; i < 4; ++i) {
      ot0[i] = __shfl_xor(t0[i], 8, 64);
      ot1[i] = __shfl_xor(t1[i], 8, 64);
    }
    float hh[2];
    #pragma unroll
    for (int u = 0; u < 2; ++u) {
      const int i = i0 + u;
      float zf = (q < 8) ? t0[i] : ot0[i];
      float zc = (q < 8) ? ot0[i] : t0[i];
      float zi = (q < 8) ? t1[i] : ot1[i];
      float zo = (q < 8) ? ot1[i] : t1[i];
      float fg = sigm(zf), ig = sigm(zi), og = sigm(zo);
      float Ct = tanh_f(zc);
      float& cr = u ? c1r : c0r;
      cr = fg * cr + ig * Ct;
      hh[u] = og * tanh_f(cr);
    }

    // store h: wave's 16x8 tile is ONE contiguous 256 B block (R7)
    {
      unsigned short hb0 = f2bf(hh[0]), hb1 = f2bf(hh[1]);
      unsigned o0 = (unsigned)(unsigned short)__shfl_xor((int)hb0, 1, 64);
      unsigned o1 = (unsigned)(unsigned short)__shfl_xor((int)hb1, 1, 64);
      if ((q & 1) == 0) {
        const size_t base = (size_t)(st + 1) * kHS + (size_t)cg * 512 +
                            w * 128 + (lg * 4 + i0) * 8 + jj;
        __hip_atomic_store((unsigned*)&hsx[base], ((unsigned)hb0) | (o0 << 16),
                           __ATOMIC_RELAXED, __HIP_MEMORY_SCOPE_AGENT);
        __hip_atomic_store((unsigned*)&hsx[base + 8], ((unsigned)hb1) | (o1 << 16),
                           __ATOMIC_RELAXED, __HIP_MEMORY_SCOPE_AGENT);
      }
      if (st == kL - 1) {
        dout[kOutSz + cidx] = hh[0];
        dout[kOutSz + cidx + 512] = hh[1];
        dout[kOutSz + (size_t)kN * kDH + cidx] = c0r;
        dout[kOutSz + (size_t)kN * kDH + cidx + 512] = c1r;
      }
    }

    // drain h stores, then publish flag (own 64B line)
    asm volatile("s_waitcnt vmcnt(0)" ::: "memory");
    __syncthreads();
    if (tid == 0)
      __hip_atomic_store(&flags[cg * kFP], (unsigned)(st + 1), __ATOMIC_RELAXED,
                         __HIP_MEMORY_SCOPE_AGENT);

    if (t + 1 < kT) {
      #pragma unroll
      for (int i = 0; i < 4; ++i) { zc0[i] = zn0[i]; zc1[i] = zn1[i]; }
    }
  }

  cbuf[cidx] = c0r;
  cbuf[cidx + 512] = c1r;
}

// ---------------------------------------------------------------- gemm_out
__global__ __launch_bounds__(256) void gemm_out_kernel(
    const unsigned short* __restrict__ Hs,   // hsx + 32768: h_1.. in chunked layout
    const unsigned short* __restrict__ WoT,  // [512][512] bf16 (B^T)
    const float* __restrict__ bout,
    float* __restrict__ out)                 // [32768][512] fp32
{
  __shared__ unsigned short Ash[128][40];
  __shared__ unsigned short Bsh[128][40];
  const int row0 = blockIdx.x * 128, col0 = blockIdx.y * 128;
  const int tid = threadIdx.x;
  const int lane = tid & 63, wave = tid >> 6;
  const int wr = wave >> 1, wc = wave & 1;
  const int m16 = lane & 15, kg = (lane >> 4) * 8;

  f32x4 acc[4][4] = {};

  for (int k0 = 0; k0 < 512; k0 += 32) {
    __syncthreads();
    #pragma unroll
    for (int i = 0; i < 2; ++i) {
      int idx = i * 256 + tid;
      int r = idx >> 2, kq = idx & 3;
      int grow = row0 + r;               // h row: t*64 + n  (t = step-1)
      size_t src = (size_t)(grow >> 6) * kHS + (size_t)((k0 >> 3) + kq) * 512 +
                   ((grow >> 4) & 3) * 128 + (grow & 15) * 8;
      *(uint4*)&Ash[r][kq * 8] = *(const uint4*)&Hs[src];
    }
    #pragma unroll
    for (int i = 0; i < 2; ++i) {
      int idx = i * 256 + tid;
      int c = idx >> 2, kq = idx & 3;
      *(uint4*)&Bsh[c][kq * 8] =
          *(const uint4*)&WoT[(size_t)(col0 + c) * 512 + k0 + kq * 8];
    }
    __syncthreads();
    bf16x8 fa[4], fb[4];
    #pragma unroll
    for (int mi = 0; mi < 4; ++mi) fa[mi] = *(const bf16x8*)&Ash[wr*64 + mi*16 + m16][kg];
    #pragma unroll
    for (int ni = 0; ni < 4; ++ni) fb[ni] = *(const bf16x8*)&Bsh[wc*64 + ni*16 + m16][kg];
    #pragma unroll
    for (int mi = 0; mi < 4; ++mi)
      #pragma unroll
      for (int ni = 0; ni < 4; ++ni)
        acc[mi][ni] = __builtin_amdgcn_mfma_f32_16x16x32_bf16(fa[mi], fb[ni], acc[mi][ni], 0, 0, 0);
  }
  const int rg = (lane >> 4) * 4;
  #pragma unroll
  for (int ni = 0; ni < 4; ++ni) {
    int col = col0 + wc*64 + ni*16 + m16;
    float bb = bout[col];
    #pragma unroll
    for (int mi = 0; mi < 4; ++mi)
      #pragma unroll
      for (int r = 0; r < 4; ++r)
        out[(size_t)(row0 + wr*64 + mi*16 + rg + r) * 512 + col] = acc[mi][ni][r] + bb;
  }
}

// ---------------------------------------------------------------- launch
extern "C" void kernel_launch(void* const* d_in, const int* in_sizes, int n_in,
                              void* d_out, int out_size, void* d_ws, size_t ws_size,
                              hipStream_t stream) {
  (void)in_sizes; (void)n_in; (void)out_size; (void)ws_size;
  const float* x    = (const float*)d_in[0];
  const float* h0   = (const float*)d_in[1];
  const float* c0   = (const float*)d_in[2];
  const float* Wf   = (const float*)d_in[3];
  const float* bf_  = (const float*)d_in[4];
  const float* Wc   = (const float*)d_in[5];
  const float* bc_  = (const float*)d_in[6];
  const float* Wi_  = (const float*)d_in[7];
  const float* bi_  = (const float*)d_in[8];
  const float* Wo   = (const float*)d_in[9];
  const float* bo_  = (const float*)d_in[10];
  const float* Wout = (const float*)d_in[11];
  const float* bout = (const float*)d_in[12];
  float* out = (float*)d_out;

  char* ws = (char*)d_ws;
  size_t off = 0;
  auto alloc = [&](size_t bytes) -> void* {
    void* p = ws + off;
    off += (bytes + 255) & ~(size_t)255;
    return p;
  };
  float*          ZxA = (float*)alloc((size_t)kT * kN * kG * 4);                 // 16 MB
  float*          ZxB = (float*)alloc((size_t)kT * kN * kG * 4);                 // 16 MB
  unsigned short* hsx = (unsigned short*)alloc((size_t)(kL + 1) * kN * kDH * 2); // 33.6 MB
  unsigned short* WxT = (unsigned short*)alloc((size_t)kG * 512 * 2);            // 2 MB
  unsigned short* WoT = (unsigned short*)alloc((size_t)512 * 512 * 2);           // 0.5 MB
  unsigned short* WhB = (unsigned short*)alloc((size_t)64 * 32 * 512 * 2);       // 2 MB
  float*          bg  = (float*)alloc((size_t)kG * 4);
  float*          cbf = (float*)alloc((size_t)kN * kDH * 4);
  unsigned int*   flg = (unsigned int*)alloc((size_t)64 * kFP * 4);              // 4 KB

  prep_kernel<<<1024, 256, 0, stream>>>(Wf, Wc, Wi_, Wo, bf_, bc_, bi_, bo_,
                                        Wout, h0, c0, WxT, WoT, WhB, bg, hsx, cbf, flg);
  // chunk 0's Zx
  gemm_x_kernel<<<dim3(16, 16), 256, 0, stream>>>(x, WxT, bg, ZxA);
  for (int c = 0; c < kChunks; ++c) {
    float* Zxcur = (c & 1) ? ZxB : ZxA;
    float* Zxnxt = (c & 1) ? ZxA : ZxB;
    const float* xnext = (c + 1 < kChunks)
        ? x + (size_t)(c + 1) * kT * kN * kDIN : nullptr;
    lstm_fused_kernel<<<256, 256, 0, stream>>>(
        WhB, Zxcur, hsx, cbf, c * kT, flg, out, xnext, WxT, bg, Zxnxt);
  }
  gemm_out_kernel<<<dim3(256, 4), 256, 0, stream>>>(
      hsx + (size_t)kN * kDH, WoT, bout, out);
}